// Round 4
// baseline (490.387 us; speedup 1.0000x reference)
//
#include <hip/hip_runtime.h>
#include <hip/hip_bf16.h>
#include <math.h>

#define SEQ 2048
#define HID 4096
#define NH 32
#define NKV 8
#define HD 128
#define KVG (NH / NKV)
#define NQKV 6144   // fused projection width: 4096 q + 1024 k + 1024 v

typedef __bf16 bf16x8 __attribute__((ext_vector_type(8)));
typedef float  f32x4  __attribute__((ext_vector_type(4)));

__device__ __forceinline__ unsigned short f2bf(float f) {
  union { float f; unsigned int u; } v; v.f = f;
  unsigned int r = v.u + 0x7FFFu + ((v.u >> 16) & 1u);
  return (unsigned short)(r >> 16);
}
__device__ __forceinline__ float bf2f(unsigned short h) {
  union { unsigned int u; float f; } v; v.u = ((unsigned int)h) << 16;
  return v.f;
}

__device__ __forceinline__ void glds16(const unsigned short* g, unsigned short* l) {
  __builtin_amdgcn_global_load_lds(
      (const __attribute__((address_space(1))) void*)g,
      (__attribute__((address_space(3))) void*)l, 16, 0, 0);
}

// ---------------- fp32 -> bf16: all five tensors in one launch ------------------
__global__ __launch_bounds__(256) void cvt_all(
    const float* __restrict__ H, const float* __restrict__ wq,
    const float* __restrict__ wk, const float* __restrict__ wv,
    const float* __restrict__ wo, unsigned short* __restrict__ ws)
{
  const long G1 = 1l << 20;
  const long M1 = 1l << 20;
  long g = (long)blockIdx.x * 256 + threadIdx.x;
  const float* src; unsigned short* dst; long rel;
  if      (g < 2 * G1) { src = H;  dst = ws;           rel = g;          }
  else if (g < 6 * G1) { src = wq; dst = ws + 8 * M1;  rel = g - 2 * G1; }
  else if (g < 7 * G1) { src = wk; dst = ws + 24 * M1; rel = g - 6 * G1; }
  else if (g < 8 * G1) { src = wv; dst = ws + 28 * M1; rel = g - 7 * G1; }
  else                 { src = wo; dst = ws + 32 * M1; rel = g - 8 * G1; }
  float4 v = ((const float4*)src)[rel];
  ushort4 o;
  o.x = f2bf(v.x); o.y = f2bf(v.y); o.z = f2bf(v.z); o.w = f2bf(v.w);
  ((ushort4*)dst)[rel] = o;
}

// ---------------- NT GEMM: C[M,N] = A[M,K] * B[N,K]^T, bf16 in, fp32 acc --------
template<bool F32OUT>
__global__ __launch_bounds__(256) void gemm_nt(
    const unsigned short* __restrict__ A,
    const unsigned short* __restrict__ B,
    void* __restrict__ Cv,
    int M, int N, int K)
{
  __shared__ unsigned short As[128 * 64];
  __shared__ unsigned short Bs[128 * 64];
  const int t = threadIdx.x;
  const int lane = t & 63, wid = t >> 6;
  const int quad = lane >> 4, l16 = lane & 15;
  const int wm = (wid & 1) * 64, wn = (wid >> 1) * 64;
  const int m0 = blockIdx.y * 128, n0 = blockIdx.x * 128;

  int srow[4], sgch[4];
  const unsigned short* ga[4];
  const unsigned short* gb[4];
  unsigned short* la[4];
  unsigned short* lb[4];
  #pragma unroll
  for (int j = 0; j < 4; j++) {
    int pj = (wid * 4 + j) * 64 + lane;
    srow[j] = pj >> 3;
    sgch[j] = (pj & 7) ^ (srow[j] & 7);
    ga[j] = A + (size_t)(m0 + srow[j]) * K + sgch[j] * 8;
    gb[j] = B + (size_t)(n0 + srow[j]) * K + sgch[j] * 8;
    la[j] = &As[(wid * 4 + j) * 512];
    lb[j] = &Bs[(wid * 4 + j) * 512];
  }

  const f32x4 fzero = {0.f, 0.f, 0.f, 0.f};
  f32x4 acc[4][4];
  #pragma unroll
  for (int i = 0; i < 4; i++)
    #pragma unroll
    for (int j = 0; j < 4; j++) acc[i][j] = fzero;

  for (int k0 = 0; k0 < K; k0 += 64) {
    __syncthreads();
    #pragma unroll
    for (int j = 0; j < 4; j++) {
      glds16(ga[j], la[j]);
      glds16(gb[j], lb[j]);
      ga[j] += 64; gb[j] += 64;
    }
    __syncthreads();

    #pragma unroll
    for (int ks = 0; ks < 2; ks++) {
      bf16x8 af[4], bfr[4];
      #pragma unroll
      for (int mt = 0; mt < 4; mt++) {
        int row = wm + mt * 16 + l16;
        int cp = (ks * 4 + quad) ^ (l16 & 7);
        af[mt] = *(const bf16x8*)(&As[(row * 8 + cp) * 8]);
      }
      #pragma unroll
      for (int nt = 0; nt < 4; nt++) {
        int row = wn + nt * 16 + l16;
        int cp = (ks * 4 + quad) ^ (l16 & 7);
        bfr[nt] = *(const bf16x8*)(&Bs[(row * 8 + cp) * 8]);
      }
      #pragma unroll
      for (int mt = 0; mt < 4; mt++)
        #pragma unroll
        for (int nt = 0; nt < 4; nt++)
          acc[mt][nt] = __builtin_amdgcn_mfma_f32_16x16x32_bf16(af[mt], bfr[nt], acc[mt][nt], 0, 0, 0);
    }
  }

  #pragma unroll
  for (int mt = 0; mt < 4; mt++)
    #pragma unroll
    for (int nt = 0; nt < 4; nt++)
      #pragma unroll
      for (int r = 0; r < 4; r++) {
        int row = m0 + wm + mt * 16 + quad * 4 + r;
        int col = n0 + wn + nt * 16 + l16;
        float v = acc[mt][nt][r];
        if (F32OUT) ((float*)Cv)[(size_t)row * N + col] = v;
        else        ((unsigned short*)Cv)[(size_t)row * N + col] = f2bf(v);
      }
}

// ---------------- RoPE (Q,K) + V-transpose, one launch --------------------------
__global__ __launch_bounds__(256) void rope_vtrans(
    const unsigned short* __restrict__ QKVr,
    const float* __restrict__ cosT,
    const float* __restrict__ sinT,
    unsigned short* __restrict__ Qh,
    unsigned short* __restrict__ Kh,
    unsigned short* __restrict__ Vtg)
{
  __shared__ unsigned short T[64 * 66];
  int hh = blockIdx.y;
  int bx = blockIdx.x;
  int t = threadIdx.x;
  if (hh < NH + NKV) {
    int sub = t >> 6, d2 = t & 63;
    int s = bx * 4 + sub;
    float c = cosT[s * 64 + d2], sn = sinT[s * 64 + d2];
    const unsigned short* src;
    unsigned short* dst;
    if (hh < NH) {
      src = QKVr + (size_t)s * NQKV + hh * HD;
      dst = Qh + ((size_t)hh * SEQ + s) * HD;
    } else {
      int h = hh - NH;
      src = QKVr + (size_t)s * NQKV + HID + h * HD;
      dst = Kh + ((size_t)h * SEQ + s) * HD;
    }
    unsigned int u = *(const unsigned int*)(src + 2 * d2);
    float a = bf2f((unsigned short)(u & 0xffff)), b = bf2f((unsigned short)(u >> 16));
    unsigned int o = (unsigned int)f2bf(a * c - b * sn) | ((unsigned int)f2bf(a * sn + b * c) << 16);
    *(unsigned int*)(dst + 2 * d2) = o;
  } else {
    int idx = bx >> 5;
    int kvh = idx >> 1, d0 = (idx & 1) * 64;
    int s0 = (bx & 31) * 64;
    int si = t >> 2, dchunk = t & 3;
    const unsigned short* src = QKVr + (size_t)(s0 + si) * NQKV + HID + NKV * HD + kvh * HD + d0 + dchunk * 16;
    uint4 a = *(const uint4*)src;
    uint4 b = *(const uint4*)(src + 8);
    unsigned int va[8] = {a.x, a.y, a.z, a.w, b.x, b.y, b.z, b.w};
    #pragma unroll
    for (int j = 0; j < 8; j++)
      *(unsigned int*)(&T[si * 66 + dchunk * 16 + j * 2]) = va[j];
    __syncthreads();
    int di = t >> 2, schunk = t & 3;
    unsigned short px[16];
    #pragma unroll
    for (int j = 0; j < 16; j++) px[j] = T[(schunk * 16 + j) * 66 + di];
    unsigned short* dst = Vtg + ((size_t)kvh * HD + d0 + di) * SEQ + s0 + schunk * 16;
    *(uint4*)dst = *(uint4*)px;
    *(uint4*)(dst + 8) = *(uint4*)(px + 8);
  }
}

// ---------------- Flash attention (causal), 32 q-rows per wave -------------------
// Block = 4 waves x 32q = 128 q-rows; q-tiles paired (t, 15-t) => 34 kv-iters per
// block, 256 blocks (1/CU, all co-resident). Each K/V LDS fragment read is shared
// by 2 q-groups -> 2x LDS arithmetic intensity vs r3. Fixed-shift softmax (exact).
__global__ __launch_bounds__(256) void flash_kernel(
    const unsigned short* __restrict__ Qh,
    const unsigned short* __restrict__ Kh,
    const unsigned short* __restrict__ Vtg,
    unsigned short* __restrict__ Obf)
{
  __shared__ unsigned short Ks[64 * 128];   // [kv][16 chunks], chunk c at c^(kv&15)
  __shared__ unsigned short Vs[128 * 64];   // [d][8 chunks],  chunk c at c^(d&7)
  __shared__ unsigned short Ps[4][32 * 72]; // per-wave P [q 0..31][kv 0..63], stride 72

  const int h = blockIdx.y;
  const int pairp = blockIdx.x;
  const int kvh = h / KVG;
  const int t = threadIdx.x;
  const int lane = t & 63, w = t >> 6;
  const int quad = lane >> 4, l16 = lane & 15;
  const float scale = 0.08838834764831845f;  // 1/sqrt(128)
  const float SHIFT = 8.0f;

  bf16x8 ones;
  #pragma unroll
  for (int j = 0; j < 8; j++) ones[j] = (__bf16)1.0f;

  int krow[4], kgch[4], vrow[4], vgch[4];
  unsigned short* lk[4];
  unsigned short* lv[4];
  #pragma unroll
  for (int j = 0; j < 4; j++) {
    int pj = (w * 4 + j) * 64 + lane;
    krow[j] = pj >> 4; kgch[j] = (pj & 15) ^ (krow[j] & 15);
    vrow[j] = pj >> 3; vgch[j] = (pj & 7) ^ (vrow[j] & 7);
    lk[j] = &Ks[(w * 4 + j) * 512];
    lv[j] = &Vs[(w * 4 + j) * 512];
  }

  unsigned short* Pw = Ps[w];
  const f32x4 fzero = {0.f, 0.f, 0.f, 0.f};

  #pragma unroll
  for (int pass = 0; pass < 2; pass++) {
    const int qt = pass ? (15 - pairp) : pairp;
    const int q0 = qt * 128;
    const int qw = q0 + w * 32;           // this wave's 32 q-rows

    // Q fragments, 2 groups of 16 q (B-operand: n=lane&15, k=quad*8+j)
    bf16x8 aq[2][4];
    #pragma unroll
    for (int qg = 0; qg < 2; qg++) {
      const unsigned short* Qp = Qh + ((size_t)h * SEQ + qw + qg * 16 + l16) * HD;
      #pragma unroll
      for (int ks = 0; ks < 4; ks++) aq[qg][ks] = *(const bf16x8*)(Qp + ks * 32 + quad * 8);
    }

    f32x4 o[2][8];
    #pragma unroll
    for (int qg = 0; qg < 2; qg++)
      #pragma unroll
      for (int dt = 0; dt < 8; dt++) o[qg][dt] = fzero;
    f32x4 lacc[2] = {fzero, fzero};

    const unsigned short* gk[4];
    const unsigned short* gv[4];
    #pragma unroll
    for (int j = 0; j < 4; j++) {
      gk[j] = Kh + ((size_t)kvh * SEQ + krow[j]) * HD + kgch[j] * 8;
      gv[j] = Vtg + ((size_t)kvh * HD + vrow[j]) * SEQ + vgch[j] * 8;
    }

    for (int kv0 = 0; kv0 < q0 + 128; kv0 += 64) {
      __syncthreads();
      #pragma unroll
      for (int j = 0; j < 4; j++) {
        glds16(gk[j], lk[j]);
        glds16(gv[j], lv[j]);
        gk[j] += 64 * HD;
        gv[j] += 64;
      }
      __syncthreads();

      // S^T[64kv x 32q] = K Q^T  (A=K shared across both q-groups)
      f32x4 sc[2][4];
      #pragma unroll
      for (int qg = 0; qg < 2; qg++)
        #pragma unroll
        for (int kvt = 0; kvt < 4; kvt++) sc[qg][kvt] = fzero;
      #pragma unroll
      for (int ks = 0; ks < 4; ks++)
        #pragma unroll
        for (int kvt = 0; kvt < 4; kvt++) {
          int row = kvt * 16 + l16;
          int cp = (ks * 4 + quad) ^ l16;
          bf16x8 bk = *(const bf16x8*)(&Ks[(row * 16 + cp) * 8]);
          sc[0][kvt] = __builtin_amdgcn_mfma_f32_16x16x32_bf16(bk, aq[0][ks], sc[0][kvt], 0, 0, 0);
          sc[1][kvt] = __builtin_amdgcn_mfma_f32_16x16x32_bf16(bk, aq[1][ks], sc[1][kvt], 0, 0, 0);
        }

      // P^T = exp(S*scale - SHIFT) with causal mask; b64 writes (4 consecutive kv)
      #pragma unroll
      for (int qg = 0; qg < 2; qg++) {
        int q = qw + qg * 16 + l16;
        #pragma unroll
        for (int kvt = 0; kvt < 4; kvt++) {
          unsigned short ph[4];
          #pragma unroll
          for (int r = 0; r < 4; r++) {
            int kv = kv0 + kvt * 16 + quad * 4 + r;
            float p = (kv > q) ? 0.f : __expf(fmaf(sc[qg][kvt][r], scale, -SHIFT));
            ph[r] = f2bf(p);
          }
          *(uint2*)(&Pw[(qg * 16 + l16) * 72 + kvt * 16 + quad * 4]) = *(const uint2*)ph;
        }
      }
      // Ps wave-private: lgkmcnt ordering suffices, no barrier.

      // O += P V^T ; l += P·1  (V fragment shared across both q-groups)
      #pragma unroll
      for (int ks2 = 0; ks2 < 2; ks2++) {
        bf16x8 ap0 = *(const bf16x8*)(&Pw[(l16)      * 72 + ks2 * 32 + quad * 8]);
        bf16x8 ap1 = *(const bf16x8*)(&Pw[(16 + l16) * 72 + ks2 * 32 + quad * 8]);
        lacc[0] = __builtin_amdgcn_mfma_f32_16x16x32_bf16(ap0, ones, lacc[0], 0, 0, 0);
        lacc[1] = __builtin_amdgcn_mfma_f32_16x16x32_bf16(ap1, ones, lacc[1], 0, 0, 0);
        #pragma unroll
        for (int dt = 0; dt < 8; dt++) {
          int row = dt * 16 + l16;
          int cp = (ks2 * 4 + quad) ^ (l16 & 7);
          bf16x8 bv = *(const bf16x8*)(&Vs[(row * 8 + cp) * 8]);
          o[0][dt] = __builtin_amdgcn_mfma_f32_16x16x32_bf16(ap0, bv, o[0][dt], 0, 0, 0);
          o[1][dt] = __builtin_amdgcn_mfma_f32_16x16x32_bf16(ap1, bv, o[1][dt], 0, 0, 0);
        }
      }
    }

    // epilogue: normalize, store bf16 to [s][h*128+d]
    #pragma unroll
    for (int qg = 0; qg < 2; qg++)
      #pragma unroll
      for (int dt = 0; dt < 8; dt++)
        #pragma unroll
        for (int r = 0; r < 4; r++) {
          int qq = qw + qg * 16 + quad * 4 + r;
          int d = dt * 16 + l16;
          Obf[(size_t)qq * HID + h * HD + d] = f2bf(o[qg][dt][r] / lacc[qg][r]);
        }
  }
}

extern "C" void kernel_launch(void* const* d_in, const int* in_sizes, int n_in,
                              void* d_out, int out_size, void* d_ws, size_t ws_size,
                              hipStream_t stream) {
  const float* H    = (const float*)d_in[0];
  const float* cosT = (const float*)d_in[2];
  const float* sinT = (const float*)d_in[3];
  const float* wq   = (const float*)d_in[4];
  const float* wk   = (const float*)d_in[5];
  const float* wv   = (const float*)d_in[6];
  const float* wo   = (const float*)d_in[7];

  unsigned short* ws = (unsigned short*)d_ws;
  const size_t M1 = 1u << 20;
  unsigned short* Hb   = ws;
  unsigned short* Wqkv = ws + (size_t)8  * M1;
  unsigned short* Wob  = ws + (size_t)32 * M1;
  unsigned short* QKVr = ws + (size_t)48 * M1;
  unsigned short* Qh   = ws + (size_t)8  * M1;   // alias Wqkv (dead after QKV GEMM)
  unsigned short* Kh   = ws + (size_t)16 * M1;
  unsigned short* Vtg  = ws + (size_t)18 * M1;
  unsigned short* attn = ws;                     // alias Hb

  cvt_all<<<49152, 256, 0, stream>>>(H, wq, wk, wv, wo, ws);

  gemm_nt<false><<<dim3(48, 16), 256, 0, stream>>>(Hb, Wqkv, QKVr, SEQ, NQKV, HID);

  rope_vtrans<<<dim3(512, NH + NKV + 1), 256, 0, stream>>>(QKVr, cosT, sinT, Qh, Kh, Vtg);

  flash_kernel<<<dim3(8, NH), 256, 0, stream>>>(Qh, Kh, Vtg, attn);

  gemm_nt<true><<<dim3(32, 16), 256, 0, stream>>>(attn, Wob, d_out, SEQ, HID, HID);
}